// Round 6
// baseline (319.624 us; speedup 1.0000x reference)
//
#include <hip/hip_runtime.h>
#include <hip/hip_fp16.h>

// MultiHeadAttention: B=4, S=1024, D_MODEL=1024, H=16, DK=DV=64
// d_out: out f32[4,1024,1024] (4194304) then attn f32[4,16,1024,1024] (67108864)

typedef short short8 __attribute__((ext_vector_type(8)));
typedef unsigned short ushort8 __attribute__((ext_vector_type(8)));
typedef float f32x4 __attribute__((ext_vector_type(4)));
typedef int i32x4 __attribute__((ext_vector_type(4)));

__device__ __forceinline__ unsigned short f2bf(float f) {
  unsigned int u = __float_as_uint(f);
  u += 0x7fffu + ((u >> 16) & 1u);
  return (unsigned short)(u >> 16);
}

// lgkmcnt-only barrier: lets global (vmcnt) traffic stay in flight across it
#define BAR() do { asm volatile("s_waitcnt lgkmcnt(0)" ::: "memory"); \
                   __builtin_amdgcn_s_barrier(); } while (0)

// ---------------- fp32 -> bf16 conversion for the three inputs ----------------
__global__ __launch_bounds__(256) void cvt3_kernel(
    const float* __restrict__ a, const float* __restrict__ b, const float* __restrict__ c,
    unsigned short* __restrict__ oa, unsigned short* __restrict__ ob, unsigned short* __restrict__ oc)
{
  const float* src = blockIdx.y == 0 ? a : (blockIdx.y == 1 ? b : c);
  unsigned short* dst = blockIdx.y == 0 ? oa : (blockIdx.y == 1 ? ob : oc);
  size_t i = (size_t)blockIdx.x * 256 + threadIdx.x;   // float4 index, 1048576 total
  float4 v = ((const float4*)src)[i];
  ushort4 o;
  o.x = f2bf(v.x); o.y = f2bf(v.y); o.z = f2bf(v.z); o.w = f2bf(v.w);
  ((ushort4*)dst)[i] = o;
}

// ---------------- weight transpose+convert: Wt[n][k] = bf16(W[k][n]) ----------------
__global__ void wtrans_kernel(
    const float* __restrict__ w0, const float* __restrict__ w1,
    const float* __restrict__ w2, const float* __restrict__ w3,
    unsigned short* __restrict__ o0, unsigned short* __restrict__ o1,
    unsigned short* __restrict__ o2, unsigned short* __restrict__ o3)
{
  __shared__ float tile[32][33];
  int z = blockIdx.z;
  const float* src = z == 0 ? w0 : (z == 1 ? w1 : (z == 2 ? w2 : w3));
  unsigned short* dst = z == 0 ? o0 : (z == 1 ? o1 : (z == 2 ? o2 : o3));
  int bx = blockIdx.x * 32;   // n base
  int by = blockIdx.y * 32;   // k base
  int tx = threadIdx.x, ty = threadIdx.y;   // (32,8)
#pragma unroll
  for (int i = 0; i < 4; ++i)
    tile[ty + 8 * i][tx] = src[(size_t)(by + ty + 8 * i) * 1024 + bx + tx];
  __syncthreads();
#pragma unroll
  for (int i = 0; i < 4; ++i)
    dst[(size_t)(bx + ty + 8 * i) * 1024 + by + tx] = f2bf(tile[tx][ty + 8 * i]);
}

// ---------------- shared GEMM core: C(128x128) = A[M][K] * Bt[N][K]^T, K=1024 ----------------
__device__ __forceinline__ void gemm_core(const unsigned short* __restrict__ A,
                                          const unsigned short* __restrict__ Bt,
                                          int m0, int n0, f32x4 (&acc)[4][4])
{
  __shared__ unsigned short As[128][40];  // +8 pad kills ds_read bank conflicts
  __shared__ unsigned short Bs[128][40];
  const int tid = threadIdx.x;
  const int lane = tid & 63;
  const int w = tid >> 6;
  const int wm = (w >> 1) << 6;
  const int wn = (w & 1) << 6;
  const int lr = lane & 15;
  const int lk = (lane >> 4) << 3;

  f32x4 zero = {0.f, 0.f, 0.f, 0.f};
#pragma unroll
  for (int mi = 0; mi < 4; ++mi)
#pragma unroll
    for (int ni = 0; ni < 4; ++ni) acc[mi][ni] = zero;

  for (int kt = 0; kt < 1024; kt += 32) {
    __syncthreads();
#pragma unroll
    for (int i = 0; i < 2; ++i) {
      int c = tid + (i << 8);
      int r = c >> 2, ko = (c & 3) << 3;
      *(short8*)&As[r][ko] = *(const short8*)&A[(size_t)(m0 + r) * 1024 + kt + ko];
      *(short8*)&Bs[r][ko] = *(const short8*)&Bt[(size_t)(n0 + r) * 1024 + kt + ko];
    }
    __syncthreads();
    short8 a[4], b[4];
#pragma unroll
    for (int mi = 0; mi < 4; ++mi) a[mi] = *(const short8*)&As[wm + mi * 16 + lr][lk];
#pragma unroll
    for (int ni = 0; ni < 4; ++ni) b[ni] = *(const short8*)&Bs[wn + ni * 16 + lr][lk];
#pragma unroll
    for (int mi = 0; mi < 4; ++mi)
#pragma unroll
      for (int ni = 0; ni < 4; ++ni)
        acc[mi][ni] = __builtin_amdgcn_mfma_f32_16x16x32_bf16(a[mi], b[ni], acc[mi][ni], 0, 0, 0);
  }
}

// ---------------- projection GEMM: z=0 Q (scaled 1/8), z=1 K, z=2 V (transposed store) ----------------
__global__ __launch_bounds__(256) void proj_gemm(
    const unsigned short* __restrict__ Xq, const unsigned short* __restrict__ Xk,
    const unsigned short* __restrict__ Xv,
    const unsigned short* __restrict__ Wtq, const unsigned short* __restrict__ Wtk,
    const unsigned short* __restrict__ Wtv,
    unsigned short* __restrict__ Qp, unsigned short* __restrict__ Kp,
    unsigned short* __restrict__ Vpt)
{
  const int mode = blockIdx.z;
  const unsigned short* A = mode == 0 ? Xq : (mode == 1 ? Xk : Xv);
  const unsigned short* Bt = mode == 0 ? Wtq : (mode == 1 ? Wtk : Wtv);
  const int m0 = blockIdx.y * 128;
  const int n0 = blockIdx.x * 128;

  f32x4 acc[4][4];
  gemm_core(A, Bt, m0, n0, acc);

  const int lane = threadIdx.x & 63;
  const int w = threadIdx.x >> 6;
  const int wm = (w >> 1) << 6;
  const int wn = (w & 1) << 6;
  const int lr = lane & 15;
  const int lg = lane >> 4;
  const float scale = (mode == 0) ? 0.125f : 1.0f;
  unsigned short* dst01 = (mode == 0) ? Qp : Kp;

#pragma unroll
  for (int mi = 0; mi < 4; ++mi)
#pragma unroll
    for (int ni = 0; ni < 4; ++ni)
#pragma unroll
      for (int r = 0; r < 4; ++r) {
        int m = m0 + wm + mi * 16 + (lg << 2) + r;
        int n = n0 + wn + ni * 16 + lr;
        float v = acc[mi][ni][r] * scale;
        int bb = m >> 10, ss = m & 1023, hh = n >> 6, dd = n & 63;
        if (mode < 2)
          dst01[((((size_t)bb * 16 + hh) << 10) + ss) * 64 + dd] = f2bf(v);      // [b][h][s][d]
        else
          Vpt[((((size_t)bb * 16 + hh) * 64 + dd) << 10) + ss] = f2bf(v);        // [b][h][d][s]
      }
}

// ---------------- output projection GEMM: out_lin = ctx @ W_fc (fp32 store) ----------------
__global__ __launch_bounds__(256) void fc_gemm(
    const unsigned short* __restrict__ Ctx, const unsigned short* __restrict__ Wtf,
    float* __restrict__ OutLin)
{
  const int m0 = blockIdx.y * 128;
  const int n0 = blockIdx.x * 128;
  f32x4 acc[4][4];
  gemm_core(Ctx, Wtf, m0, n0, acc);

  const int lane = threadIdx.x & 63;
  const int w = threadIdx.x >> 6;
  const int wm = (w >> 1) << 6;
  const int wn = (w & 1) << 6;
  const int lr = lane & 15;
  const int lg = lane >> 4;
#pragma unroll
  for (int mi = 0; mi < 4; ++mi)
#pragma unroll
    for (int ni = 0; ni < 4; ++ni)
#pragma unroll
      for (int r = 0; r < 4; ++r) {
        int m = m0 + wm + mi * 16 + (lg << 2) + r;
        int n = n0 + wn + ni * 16 + lr;
        OutLin[(size_t)m * 1024 + n] = acc[mi][ni][r];
      }
}

// ---------------- fused attention ----------------
// 16 q-rows per block, 4 waves, 32 KB LDS.
// phase 1: QK^T MFMA + res_att/mask folded at the MFMA output site ->
//          S16 holds FINAL masked score (fp16; masked = -30000 -> exp==0).
//          16 independent iterations x ~10 loads each = natural latency hiding.
// phase 2: pure LDS+VALU softmax (no global reads in the serial chain),
//          writes attn (f32) and in-place bf16 P.
// phase 3: PV MFMA from LDS P and L2-resident V^T.
__global__ __launch_bounds__(256) void attn_kernel(
    const unsigned short* __restrict__ Qp, const unsigned short* __restrict__ Kp,
    const unsigned short* __restrict__ Vpt,
    const float* __restrict__ res_att, const int* __restrict__ mask,
    float* __restrict__ attn_out, unsigned short* __restrict__ Ctx)
{
  __shared__ unsigned short S16[16 * 1024];   // 32 KB
  const int qb = blockIdx.x, h = blockIdx.y, b = blockIdx.z;
  const int q0 = qb * 16;
  const int tid = threadIdx.x;
  const int lane = tid & 63;
  const int w = tid >> 6;
  const int lr = lane & 15;
  const int lg = lane >> 4;
  const int lk = lg << 3;

  const unsigned short* Qbh = Qp + (((size_t)b * 16 + h) << 16);
  const unsigned short* Kbh = Kp + (((size_t)b * 16 + h) << 16);
  const unsigned short* Vbh = Vpt + (((size_t)b * 16 + h) << 16);
  const float* res_row = res_att + ((((size_t)b * 16 + h) * 1024 + q0) << 10);
  const int* msk_row = mask + ((((size_t)b) * 1024 + q0) << 10);
  float* attn_row = attn_out + ((((size_t)b * 16 + h) * 1024 + q0) << 10);

  // Q fragments (Q pre-scaled by 1/8 at projection)
  short8 aq0 = *(const short8*)&Qbh[(size_t)(q0 + lr) * 64 + lk];
  short8 aq1 = *(const short8*)&Qbh[(size_t)(q0 + lr) * 64 + 32 + lk];

  // ---- phase 1: scores + bias + mask -> fp16 LDS. wave w: cols [256w, 256w+256) ----
  f32x4 zero = {0.f, 0.f, 0.f, 0.f};
#pragma unroll 2
  for (int t = 0; t < 16; ++t) {
    int n0 = (w * 16 + t) * 16;
    short8 bk0 = *(const short8*)&Kbh[(size_t)(n0 + lr) * 64 + lk];
    short8 bk1 = *(const short8*)&Kbh[(size_t)(n0 + lr) * 64 + 32 + lk];
    int col = n0 + lr;
    // independent bias loads (res NT: zero reuse; mask regular: reused by 16 heads)
    float rr0 = __builtin_nontemporal_load(&res_row[((size_t)(lg * 4 + 0) << 10) + col]);
    float rr1 = __builtin_nontemporal_load(&res_row[((size_t)(lg * 4 + 1) << 10) + col]);
    float rr2 = __builtin_nontemporal_load(&res_row[((size_t)(lg * 4 + 2) << 10) + col]);
    float rr3 = __builtin_nontemporal_load(&res_row[((size_t)(lg * 4 + 3) << 10) + col]);
    int mm0 = msk_row[((size_t)(lg * 4 + 0) << 10) + col];
    int mm1 = msk_row[((size_t)(lg * 4 + 1) << 10) + col];
    int mm2 = msk_row[((size_t)(lg * 4 + 2) << 10) + col];
    int mm3 = msk_row[((size_t)(lg * 4 + 3) << 10) + col];
    f32x4 acc = zero;
    acc = __builtin_amdgcn_mfma_f32_16x16x32_bf16(aq0, bk0, acc, 0, 0, 0);
    acc = __builtin_amdgcn_mfma_f32_16x16x32_bf16(aq1, bk1, acc, 0, 0, 0);
    float s0 = mm0 ? -30000.f : acc[0] + rr0;
    float s1 = mm1 ? -30000.f : acc[1] + rr1;
    float s2 = mm2 ? -30000.f : acc[2] + rr2;
    float s3 = mm3 ? -30000.f : acc[3] + rr3;
    int cbase = (((col >> 3) ^ ((lg * 4) & 7)) << 3) | (col & 7);   // swz depends on row&7
#pragma unroll
    for (int r = 0; r < 4; ++r) {
      int row = lg * 4 + r;
      int idx = row * 1024 + ((((col >> 3) ^ (row & 7)) << 3) | (col & 7));
      float sv = (r == 0) ? s0 : (r == 1) ? s1 : (r == 2) ? s2 : s3;
      S16[idx] = __half_as_ushort(__float2half(sv));
    }
    (void)cbase;
  }

  BAR();

  // ---- phase 2: pure-LDS softmax; whole wave per row; rows w, w+4, w+8, w+12 ----
#pragma unroll
  for (int j = 0; j < 4; ++j) {
    const int r_ = w + 4 * j;
    const int swz_ = r_ & 7;
    ushort8 hv0 = *(const ushort8*)&S16[r_ * 1024 + ((lane ^ swz_) << 3)];
    ushort8 hv1 = *(const ushort8*)&S16[r_ * 1024 + (((64 + lane) ^ swz_) << 3)];
    float sv[16];
#pragma unroll
    for (int e = 0; e < 8; ++e) {
      sv[e]     = __expf(__half2float(__ushort_as_half(hv0[e])));
      sv[8 + e] = __expf(__half2float(__ushort_as_half(hv1[e])));
    }
    float s01 = sv[0] + sv[1], s23 = sv[2] + sv[3];
    float s45 = sv[4] + sv[5], s67 = sv[6] + sv[7];
    float s89 = sv[8] + sv[9], sab = sv[10] + sv[11];
    float scd = sv[12] + sv[13], sef = sv[14] + sv[15];
    float sum = ((s01 + s23) + (s45 + s67)) + ((s89 + sab) + (scd + sef));
#pragma unroll
    for (int off = 32; off >= 1; off >>= 1) sum += __shfl_xor(sum, off);
    float inv = 1.f / sum;
#pragma unroll
    for (int i = 0; i < 16; ++i) sv[i] *= inv;
    f32x4* att4 = (f32x4*)(attn_row + ((size_t)r_ << 10));
    f32x4 o0 = {sv[0], sv[1], sv[2], sv[3]};
    f32x4 o1 = {sv[4], sv[5], sv[6], sv[7]};
    f32x4 o2 = {sv[8], sv[9], sv[10], sv[11]};
    f32x4 o3 = {sv[12], sv[13], sv[14], sv[15]};
    // cols: hv0 -> [8*lane, 8*lane+8), hv1 -> [512+8*lane, ...)
    att4[lane * 2] = o0;
    att4[lane * 2 + 1] = o1;
    att4[128 + lane * 2] = o2;
    att4[128 + lane * 2 + 1] = o3;
    ushort8 q0_, q1_;
#pragma unroll
    for (int e = 0; e < 8; ++e) { q0_[e] = f2bf(sv[e]); q1_[e] = f2bf(sv[8 + e]); }
    *(ushort8*)&S16[r_ * 1024 + ((lane ^ swz_) << 3)] = q0_;
    *(ushort8*)&S16[r_ * 1024 + (((64 + lane) ^ swz_) << 3)] = q1_;
  }

  BAR();

  // ---- phase 3: context = P @ V; wave w computes dv-tile [16w, 16w+16) ----
  f32x4 co = zero;
  const int dv0 = w * 16;
  const int pswz = lr & 7;
#pragma unroll 4
  for (int ks = 0; ks < 32; ++ks) {
    int u = (ks << 2) + lg;                      // 16B unit along k
    short8 pa = *(const short8*)&S16[lr * 1024 + ((u ^ pswz) << 3)];
    short8 bv = *(const short8*)&Vbh[(size_t)(dv0 + lr) * 1024 + (ks << 5) + lk];
    co = __builtin_amdgcn_mfma_f32_16x16x32_bf16(pa, bv, co, 0, 0, 0);
  }
#pragma unroll
  for (int r = 0; r < 4; ++r) {
    int row = (lg << 2) + r;
    Ctx[((size_t)(b * 1024 + q0 + row)) * 1024 + h * 64 + dv0 + lr] = f2bf(co[r]);
  }
}

// ---------------- residual + LayerNorm ----------------
__global__ __launch_bounds__(256) void ln_kernel(
    const float* __restrict__ xlin, const float* __restrict__ resid,
    const float* __restrict__ gamma, const float* __restrict__ beta,
    float* __restrict__ out)
{
  const int m = blockIdx.x;
  const int t = threadIdx.x;
  float4 v = ((const float4*)(xlin + ((size_t)m << 10)))[t];
  float4 rq = ((const float4*)(resid + ((size_t)m << 10)))[t];
  v.x += rq.x; v.y += rq.y; v.z += rq.z; v.w += rq.w;
  float s = v.x + v.y + v.z + v.w;
  float s2 = v.x * v.x + v.y * v.y + v.z * v.z + v.w * v.w;
#pragma unroll
  for (int off = 32; off >= 1; off >>= 1) {
    s += __shfl_xor(s, off);
    s2 += __shfl_xor(s2, off);
  }
  __shared__ float rs[4], rs2[4];
  const int w = t >> 6, lane = t & 63;
  if (lane == 0) { rs[w] = s; rs2[w] = s2; }
  __syncthreads();
  s = rs[0] + rs[1] + rs[2] + rs[3];
  s2 = rs2[0] + rs2[1] + rs2[2] + rs2[3];
  float mu = s * (1.f / 1024.f);
  float var = s2 * (1.f / 1024.f) - mu * mu;
  float rstd = rsqrtf(var + 1e-5f);
  float4 g = ((const float4*)gamma)[t];
  float4 bt = ((const float4*)beta)[t];
  float4 o;
  o.x = (v.x - mu) * rstd * g.x + bt.x;
  o.y = (v.y - mu) * rstd * g.y + bt.y;
  o.z = (v.z - mu) * rstd * g.z + bt.z;
  o.w = (v.w - mu) * rstd * g.w + bt.w;
  ((float4*)(out + ((size_t)m << 10)))[t] = o;
}

extern "C" void kernel_launch(void* const* d_in, const int* in_sizes, int n_in,
                              void* d_out, int out_size, void* d_ws, size_t ws_size,
                              hipStream_t stream) {
  const float* inQ = (const float*)d_in[0];
  const float* inK = (const float*)d_in[1];
  const float* inV = (const float*)d_in[2];
  const int* msk = (const int*)d_in[3];
  const float* res = (const float*)d_in[4];
  const float* wq = (const float*)d_in[5];
  const float* wk = (const float*)d_in[6];
  const float* wv = (const float*)d_in[7];
  const float* wfc = (const float*)d_in[8];
  const float* gamma = (const float*)d_in[9];
  const float* beta = (const float*)d_in[10];

  // workspace layout (OutLin aliases the dead Xq/Xk region)
  unsigned short* Xq = (unsigned short*)d_ws;          // 4194304 bf16
  unsigned short* Xk = Xq + 4194304;
  unsigned short* Xv = Xk + 4194304;
  unsigned short* Wtq = Xv + 4194304;                  // 1048576 bf16 each
  unsigned short* Wtk = Wtq + 1048576;
  unsigned short* Wtv = Wtk + 1048576;
  unsigned short* Wtf = Wtv + 1048576;
  unsigned short* Qp = Wtf + 1048576;                  // 4194304 bf16 each
  unsigned short* Kp = Qp + 4194304;
  unsigned short* Vpt = Kp + 4194304;
  unsigned short* Ctx = Vpt + 4194304;
  float* OutLin = (float*)d_ws;                        // reuses Xq/Xk (dead after proj_gemm)

  float* out = (float*)d_out;
  float* attn_out = out + 4194304;

  cvt3_kernel<<<dim3(4096, 3, 1), 256, 0, stream>>>(inQ, inK, inV, Xq, Xk, Xv);
  wtrans_kernel<<<dim3(32, 32, 4), dim3(32, 8, 1), 0, stream>>>(wq, wk, wv, wfc, Wtq, Wtk, Wtv, Wtf);
  proj_gemm<<<dim3(8, 32, 3), 256, 0, stream>>>(Xq, Xk, Xv, Wtq, Wtk, Wtv, Qp, Kp, Vpt);
  attn_kernel<<<dim3(64, 16, 4), 256, 0, stream>>>(Qp, Kp, Vpt, res, msk, attn_out, Ctx);
  fc_gemm<<<dim3(8, 32, 1), 256, 0, stream>>>(Ctx, Wtf, OutLin);
  ln_kernel<<<dim3(4096, 1, 1), 256, 0, stream>>>(OutLin, inQ, gamma, beta, out);
}